// Round 10
// baseline (582.754 us; speedup 1.0000x reference)
//
#include <hip/hip_runtime.h>
#include <math.h>

// ConvGRU v18: = v17 (publish-early + locality-split chunks) with the d_out
// ALIASING RACE fixed.
// v17 post-mortem: absmax 1.98 = h-value scale. hbuf0 aliased d_out; the
// wavefront skew (|t(y)-t(y')| up to |y-y'|) let a lagging block's
// top-of-step-63 publish of h(62) into d_out land AFTER a leading block's
// final NCHW write to the same bytes. v11 had the same latent race with 2
// steps of slack (passed on luck). v18: BOTH parity h buffers live in d_ws;
// d_out is write-only, written once per element at t=63.
// ws: [0,2MB) hbuf0, [2MB,4MB) hbuf1, +4MB wfrag (72KB), +4MB+80KB flags.
// Total 4.08MB <= proven envelope (v15 passed at this size).
//
// Structure (v17):
//  - publish h(t-1) at TOP of step t (from hrow LDS, 1 st_dc4/thread);
//    dump+drain+flag overlap the consumer's local staging.
//  - chunks split by locality: 20 local (x rows 0-47, own-h rows 48-79)
//    run BEFORE the poll; 16 remote (ky0 rows 80-111 = h(y-1), ky2 rows
//    112-143 = h(y+1)) after halo load. Weights per v15's verified grouping.
//  - per-wave drain->flag (8 adds/dir/step, poll target 8t).
//  - parity-2 buffers race-free: y's flag at top of t+1 is posted after its
//    halo read at t; neighbor's publish of h(t+1) (top of t+2) requires
//    poll >= 8(t+1) -> transitively ordered after y's read of h(t-1).
//  - deadlock-free: flags posted unconditionally before any poll.
//  - x(t+1) prefetch after B2' drains under the epilogue.

typedef _Float16 half8 __attribute__((ext_vector_type(8)));
typedef float floatx16 __attribute__((ext_vector_type(16)));
typedef float floatx4 __attribute__((ext_vector_type(4)));

#define RS 144                       // bytes per staged k-row (both copies)
#define CP1 (144 * RS)               // copy1 byte base (20736)
#define SCRDW (2 * 144 * 36)         // scratch dword base (10368)
#define LDS_DW (SCRDW + 4 * 16 * 68) // + 4 tiles x 16 regs x 68-stride (14720)

static __device__ __forceinline__ unsigned pack2(float a, float b) {
    _Float16 ha = (_Float16)a, hb = (_Float16)b;
    unsigned short ua = *(unsigned short*)&ha, ub = *(unsigned short*)&hb;
    return (unsigned)ua | ((unsigned)ub << 16);
}

// device-coherent (sc0 sc1) ops: L1/L2 bypass, served at device coherence pt
static __device__ __forceinline__ void st_dc4(float* p, floatx4 v) {
    asm volatile("global_store_dwordx4 %0, %1, off sc0 sc1"
                 :: "v"(p), "v"(v) : "memory");
}
static __device__ __forceinline__ void drain_vm() {
    asm volatile("s_waitcnt vmcnt(0)" ::: "memory");
}
static __device__ __forceinline__ floatx4 ld_dc4(const float* p) {
    floatx4 a;
    asm volatile("global_load_dwordx4 %0, %1, off sc0 sc1\n\t"
                 "s_waitcnt vmcnt(0)"
                 : "=v"(a) : "v"(p));
    return a;
}
static __device__ __forceinline__ void ld_dc4_2(const float* p0, const float* p1,
                                                floatx4& a, floatx4& b) {
    asm volatile("global_load_dwordx4 %0, %2, off sc0 sc1\n\t"
                 "global_load_dwordx4 %1, %3, off sc0 sc1\n\t"
                 "s_waitcnt vmcnt(0)"
                 : "=&v"(a), "=&v"(b) : "v"(p0), "v"(p1));
}

// x slice loader (tasks 0..767 = 48 rows x 16 granules over 512 threads)
static __device__ __forceinline__ void load_x(const float* __restrict__ x,
                                              int b, int y, int t, int tx,
                                              float4& a, float4& c) {
    {
        const int rr = tx >> 4, g = tx & 15;
        const int cin = rr / 3, ky = rr - cin * 3, ys = y + ky - 1;
        a = make_float4(0.f, 0.f, 0.f, 0.f);
        if ((unsigned)ys < 64u)
            a = *(const float4*)(x + (((size_t)(b * 16 + cin) * 64 + t) * 4096)
                                   + ys * 64 + g * 4);
    }
    c = make_float4(0.f, 0.f, 0.f, 0.f);
    if (tx < 256) {
        const int task = 512 + tx, rr = task >> 4, g = task & 15;
        const int cin = rr / 3, ky = rr - cin * 3, ys = y + ky - 1;
        if ((unsigned)ys < 64u)
            c = *(const float4*)(x + (((size_t)(b * 16 + cin) * 64 + t) * 4096)
                                   + ys * 64 + g * 4);
    }
}

// ---- pre-kernel: weights -> A-frags, v15-verified locality grouping ----
// chunks: 0..11 x (rows rl=cin*3+ky); 12..19 ky1 (own h); 20..27 ky0 (y-1);
// 28..35 ky2 (y+1). Per-row 4 k-slots (q,o), kx=o+2q, phantom at q&o.
__global__ __launch_bounds__(64) void build_wfrag(
    const float* __restrict__ Wx, const float* __restrict__ Wh,
    uint4* __restrict__ wfrag)
{
    const int bid   = blockIdx.x;            // 0..71
    const int mtile = bid / 36, c = bid % 36;
    const int lane  = threadIdx.x;
    const int m     = lane & 31;
    const int grow  = (m < 16) ? (mtile * 16 + m) : (64 + mtile * 16 + (m - 16));
    unsigned short h[8];
    for (int j = 0; j < 8; ++j) {
        const int kl = (lane >> 5) * 8 + j;
        float w = 0.0f;
        if (c < 12) {
            const int k  = c * 16 + kl;
            const int rl = k >> 2, t4 = k & 3;
            const int cin = rl / 3, ky = rl - cin * 3;
            const int o = t4 & 1, q = t4 >> 1, kx = o + 2 * q;
            if (!(q && o)) w = Wx[((size_t)grow * 16 + cin) * 9 + ky * 3 + kx];
        } else {
            const int cg = (c - 12) >> 3;    // 0:ky1 1:ky0 2:ky2
            const int ky = (cg == 0) ? 1 : ((cg == 1) ? 0 : 2);
            const int k  = ((c - 12) & 7) * 16 + kl;
            const int cin = k >> 2, t4 = k & 3;
            const int o = t4 & 1, q = t4 >> 1, kx = o + 2 * q;
            if (!(q && o)) w = Wh[((size_t)grow * 32 + cin) * 9 + ky * 3 + kx];
        }
        _Float16 hw = (_Float16)w;
        h[j] = *(unsigned short*)&hw;
    }
    uint4 o4;
    o4.x = (unsigned)h[0] | ((unsigned)h[1] << 16);
    o4.y = (unsigned)h[2] | ((unsigned)h[3] << 16);
    o4.z = (unsigned)h[4] | ((unsigned)h[5] << 16);
    o4.w = (unsigned)h[6] | ((unsigned)h[7] << 16);
    wfrag[(size_t)bid * 64 + lane] = o4;
}

#define STAGE_ROW(rr, vx, vy, vz, vw)                              \
    do {                                                           \
        float prev_ = __shfl_up((vw), 1);                          \
        if (g == 0) prev_ = 0.f;                                   \
        const int r36_ = (rr) * 36;                                \
        plds[r36_ + 2 * g + 2] = pack2((vx), (vy));                \
        plds[r36_ + 2 * g + 3] = pack2((vz), (vw));                \
        plds[CP1 / 4 + r36_ + 2 * g]     = pack2(prev_, (vx));     \
        plds[CP1 / 4 + r36_ + 2 * g + 1] = pack2((vy), (vz));      \
        if (g == 15) plds[CP1 / 4 + r36_ + 32] = pack2((vw), 0.f); \
    } while (0)

#define MFMA_CHUNK(cc, rbb)                                                  \
    do {                                                                     \
        uint4 aw = wlds[(mtile * 36 + (cc)) * 64 + lane];                    \
        const int B0 = (rbb) * RS;                                           \
        unsigned d0 = *(const unsigned*)(lbase + B0);                        \
        unsigned d1 = *(const unsigned*)(lbase + B0 + 4);                    \
        unsigned e0 = *(const unsigned*)(lbase + B0 + RS);                   \
        unsigned e1 = *(const unsigned*)(lbase + B0 + RS + 4);               \
        uint4 bf; bf.x = d0; bf.y = d1; bf.z = e0; bf.w = e1;                \
        union { uint4 u; half8 h; } ua, ub;                                  \
        ua.u = aw; ub.u = bf;                                                \
        acc = __builtin_amdgcn_mfma_f32_32x32x16_f16(ua.h, ub.h, acc, 0, 0, 0); \
    } while (0)

__global__ __launch_bounds__(512, 1) void convgru_persist(
    const float* __restrict__ x, const float* __restrict__ bx,
    const uint4* __restrict__ wfrag,
    float* __restrict__ hbuf0,   // parity-0 h buffer (ws, raw layout)
    float* __restrict__ hbuf1,   // parity-1 h buffer (ws)
    float* __restrict__ out,     // final NCHW (t=63 ONLY; never aliased)
    int* __restrict__ flags)     // inbox[b][y][2]: [0]=from y-1, [1]=from y+1
{
    __shared__ unsigned plds[LDS_DW];        // staging + scratch (58,880 B)
    __shared__ uint4    wlds[72 * 64];       // A-fragments      (73,728 B)
    __shared__ float    hrow[32 * 64];       // own h(t-1)       ( 8,192 B)

    const int tx = threadIdx.x;
    const int y  = blockIdx.x;               // image row 0..63
    const int b  = blockIdx.y;               // batch 0..3
    const int lane  = tx & 63;
    const int wv    = tx >> 6;               // 0..7
    const int tile  = wv & 3;
    const int mtile = tile & 1;
    const int ntile = tile >> 1;
    const int role  = wv >> 2;               // 0 = A (epilogue), 1 = B (park)
    const int xpx   = ntile * 32 + (lane & 31);
    const int half  = lane >> 5;
    const int lb_off = ((xpx & 1) ? (2 * xpx + 6) : (CP1 + 2 * xpx))
                       + half * (2 * RS);
    const char* lbase = (const char*)plds + lb_off;

    // one-time setup
    #pragma unroll
    for (int i = 0; i < 9; ++i) wlds[i * 512 + tx] = wfrag[i * 512 + tx];
    if (tx < 144) plds[tx * 36 + 34] = 0u;           // copy0 right-halo dword
    ((float4*)hrow)[tx] = make_float4(0.f, 0.f, 0.f, 0.f);   // h0 = 0
    __syncthreads();

    int* const inbox = flags + (b * 64 + y) * 2;

    float hcur[8];
    #pragma unroll
    for (int r = 0; r < 8; ++r) hcur[r] = 0.0f;
    float bz[8], bn[8];
    #pragma unroll
    for (int r = 0; r < 8; ++r) {
        const int row = (r & 3) + 8 * (r >> 2) + 4 * half;
        const int oc  = mtile * 16 + row;
        bz[r] = bx[oc]; bn[r] = bx[64 + oc];
    }

    float4 xv0, xv1;
    load_x(x, b, y, 0, tx, xv0, xv1);                // prefetch t=0

    #pragma unroll 1
    for (int t = 0; t < 64; ++t) {
        float* const pbuf = ((t - 1) & 1) ? hbuf1 : hbuf0;   // h(t-1) slot

        // ---- TOP: publish h(t-1) (dump hrow), then stage local ----
        if (t > 0)
            st_dc4(pbuf + ((size_t)(b * 64 + y) * 2048) + tx * 4,
                   ((floatx4*)hrow)[tx]);

        {   // x -> LDS rows 0..47 (from prefetched regs)
            const int g = tx & 15;
            const int rr = tx >> 4;
            STAGE_ROW(rr, xv0.x, xv0.y, xv0.z, xv0.w);
        }
        if (tx < 256) {
            const int g = tx & 15;
            const int rr = (512 + tx) >> 4;
            STAGE_ROW(rr, xv1.x, xv1.y, xv1.z, xv1.w);
        }
        {   // own-h -> LDS rows 48..79 (from hrow)
            const int cin = tx >> 4, g = tx & 15;
            float4 v = *(const float4*)(hrow + cin * 64 + g * 4);
            STAGE_ROW(48 + cin, v.x, v.y, v.z, v.w);
        }
        if (t > 0) {
            drain_vm();                              // own dump at L3
            if (lane == 0) {                         // per-wave flags (8/dir)
                if (y < 63)
                    __hip_atomic_fetch_add(flags + (b * 64 + y + 1) * 2 + 0, 1,
                                           __ATOMIC_RELAXED, __HIP_MEMORY_SCOPE_AGENT);
                if (y > 0)
                    __hip_atomic_fetch_add(flags + (b * 64 + y - 1) * 2 + 1, 1,
                                           __ATOMIC_RELAXED, __HIP_MEMORY_SCOPE_AGENT);
            }
        }
        __syncthreads();                             // B1: local staging done

        // ---- local chunks (no neighbor dependency) ----
        floatx16 acc;
        #pragma unroll
        for (int i = 0; i < 16; ++i) acc[i] = 0.0f;
        if (role == 0) {
            #pragma unroll
            for (int j = 0; j < 10; ++j) MFMA_CHUNK(j, 4 * j);
        } else {
            #pragma unroll
            for (int j = 0; j < 10; ++j) {
                const int c = 10 + j;
                MFMA_CHUNK(c, (c < 12) ? 4 * c : 48 + 4 * (c - 12));
            }
        }

        // ---- poll neighbors' h(t-1) (flag posted at their step top) ----
        if (t > 0) {
            if (lane < 2) {
                const bool valid = lane ? (y < 63) : (y > 0);
                if (valid) {
                    while (__hip_atomic_load(inbox + lane, __ATOMIC_RELAXED,
                                             __HIP_MEMORY_SCOPE_AGENT) < 8 * t) { }
                }
            }
            __builtin_amdgcn_sched_barrier(0);       // pin loads after spin
        }

        // ---- halo load + stage remote rows 80..143 ----
        {
            const int cin = tx >> 4, g = tx & 15;
            floatx4 vm = (floatx4)(0.f), vp = (floatx4)(0.f);
            if (t > 0) {
                const float* pm = pbuf + ((size_t)(b * 64 + (y - 1)) * 2048)
                                       + cin * 64 + g * 4;
                const float* pp = pbuf + ((size_t)(b * 64 + (y + 1)) * 2048)
                                       + cin * 64 + g * 4;
                if (y == 0)       vp = ld_dc4(pp);
                else if (y == 63) vm = ld_dc4(pm);
                else              ld_dc4_2(pm, pp, vm, vp);
            }
            STAGE_ROW(80 + cin, vm[0], vm[1], vm[2], vm[3]);
            STAGE_ROW(112 + cin, vp[0], vp[1], vp[2], vp[3]);
        }
        __syncthreads();                             // B2: remote staging done

        // ---- remote chunks ----
        if (role == 0) {
            #pragma unroll
            for (int j = 0; j < 8; ++j) MFMA_CHUNK(20 + j, 80 + 4 * j);
        } else {
            #pragma unroll
            for (int j = 0; j < 8; ++j) MFMA_CHUNK(28 + j, 112 + 4 * j);
            #pragma unroll
            for (int r = 0; r < 16; ++r)
                plds[SCRDW + tile * 1088 + r * 68 + lane] = __float_as_uint(acc[r]);
        }
        __syncthreads();                             // B2': scratch handoff

        // ---- x(t+1) prefetch (drains under epilogue) ----
        if (t < 63) load_x(x, b, y, t + 1, tx, xv0, xv1);

        // ---- role A: combine + epilogue ----
        if (role == 0) {
            #pragma unroll
            for (int r = 0; r < 16; ++r)
                acc[r] += __uint_as_float(plds[SCRDW + tile * 1088 + r * 68 + lane]);
            #pragma unroll
            for (int r = 0; r < 8; ++r) {
                const int row = (r & 3) + 8 * (r >> 2) + 4 * half;
                const int oc  = mtile * 16 + row;
                float zp = acc[r]     + bz[r];
                float np = acc[r + 8] + bn[r];
                float z  = 1.0f / (1.0f + __expf(-zp));
                float e  = __expf(2.0f * np);
                float n  = 1.0f - 2.0f / (e + 1.0f);             // tanh
                float hn = (1.0f - z) * hcur[r] + z * n;
                hcur[r] = hn;
                if (t == 63)
                    out[(size_t)(b * 32 + oc) * 4096 + y * 64 + xpx] = hn;
                else
                    hrow[oc * 64 + xpx] = hn;
            }
        }
        __syncthreads();                             // B3: hrow ready
    }
}

extern "C" void kernel_launch(void* const* d_in, const int* in_sizes, int n_in,
                              void* d_out, int out_size, void* d_ws, size_t ws_size,
                              hipStream_t stream) {
    const float* x  = (const float*)d_in[0];
    const float* Wx = (const float*)d_in[1];
    const float* bx = (const float*)d_in[2];
    const float* Wh = (const float*)d_in[3];
    float* out   = (float*)d_out;                            // write-only
    float* hbuf0 = (float*)d_ws;                             // parity-0 (2 MB)
    float* hbuf1 = (float*)((char*)d_ws + (2u << 20));       // parity-1 (2 MB)
    uint4* wfrag = (uint4*)((char*)d_ws + (4u << 20));       // 72 KB A-frags
    int*   flags = (int*)((char*)d_ws + (4u << 20) + (80u << 10)); // 2 KB

    (void)hipMemsetAsync(flags, 0, 2048, stream);
    hipLaunchKernelGGL(build_wfrag, dim3(72), dim3(64), 0, stream, Wx, Wh, wfrag);

    void* args[] = { (void*)&x, (void*)&bx, (void*)&wfrag,
                     (void*)&hbuf0, (void*)&hbuf1, (void*)&out, (void*)&flags };
    (void)hipLaunchCooperativeKernel((const void*)convgru_persist,
                                     dim3(64, 4), dim3(512), args, 0, stream);
}

// Round 11
// 508.906 us; speedup vs baseline: 1.1451x; 1.1451x over previous
//
#include <hip/hip_runtime.h>
#include <math.h>

// ConvGRU v19: persistent wavefront; DEDICATED PUBLISHER WAVE + f16 h
// transport + issue-early/wait-late halo.
// v18 post-mortem: block-wide publish+drain before B1 put a full coherence
// leg on every wave's path (489us). v19:
//  - wave 7 ALONE publishes h(t-1) as packed f16 (4KB/row) at step top,
//    drains, stores monotonic flag[b][y] = t. Waves 0-6 stage x + own-h
//    concurrently -> publish leg off the block critical path.
//    (f16 transport is lossless: published h is only consumed as f16 GEMM
//    B-input; same single f32->f16 rounding as the old in-block pack2.)
//  - halo = ONE dwordx4/thread (2 rows x 4KB f16), ISSUED before local MFMA,
//    vmcnt(0) after (T14 issue-early/wait-late); staged to rows 80..143 as
//    copy0 = raw f16 dwords, copy1 = 16-bit alignbit pairs (bit-identical
//    to the old f32 STAGE_ROW output).
//  - local/remote chunk split per v15/v18-verified weights: kh0 = 12 x-chunks
//    + 8 ky0 (rows 80-111); kh1 = 8 own-h + 8 ky2 (rows 112-143); single acc.
//  - parity-2 f16 slots in d_ws (1MB each); d_out write-only at t=63.
//    Race-free: y+1's publish of h(t+1) at top of t+2 is gated by its t+1
//    poll of flag[y]>=t+1, stored after y's step-t halo read (B3-ordered).
//  - per-wave poll (lanes 0/1), x(t+1) prefetch at B2' drains under epilogue.
// ws: [0,2MB) f16 slots, +2MB wfrag (72KB), +2MB+80KB flags (1KB).

typedef _Float16 half8 __attribute__((ext_vector_type(8)));
typedef float floatx16 __attribute__((ext_vector_type(16)));
typedef unsigned uintx4 __attribute__((ext_vector_type(4)));

#define RS 144                       // bytes per staged k-row (both copies)
#define CP1 (144 * RS)               // copy1 byte base (20736)
#define SCRDW (2 * 144 * 36)         // scratch dword base (10368)
#define LDS_DW (SCRDW + 4 * 16 * 68) // + 4 tiles x 16 regs x 68-stride (14720)
#define SLOTDW (4 * 64 * 1024)       // dwords per f16 parity slot (1 MB)

static __device__ __forceinline__ unsigned pack2(float a, float b) {
    _Float16 ha = (_Float16)a, hb = (_Float16)b;
    unsigned short ua = *(unsigned short*)&ha, ub = *(unsigned short*)&hb;
    return (unsigned)ua | ((unsigned)ub << 16);
}

// device-coherent (sc0 sc1) ops
static __device__ __forceinline__ void st_dc4u(unsigned* p, uintx4 v) {
    asm volatile("global_store_dwordx4 %0, %1, off sc0 sc1"
                 :: "v"(p), "v"(v) : "memory");
}
static __device__ __forceinline__ void drain_vm() {
    asm volatile("s_waitcnt vmcnt(0)" ::: "memory");
}
static __device__ __forceinline__ void ld_issue4(const unsigned* p, uintx4& a) {
    asm volatile("global_load_dwordx4 %0, %1, off sc0 sc1"
                 : "+v"(a) : "v"(p));               // issue only; no waitcnt
}
static __device__ __forceinline__ void vm_wait4(uintx4& a) {
    asm volatile("s_waitcnt vmcnt(0)" : "+v"(a));   // data-dep ties reads after
}

// x slice prefetch for waves 0-6: tasks u=tx (0..447) and u=448+tx (tx<320)
static __device__ __forceinline__ void load_x7(const float* __restrict__ x,
                                               int b, int y, int t, int tx,
                                               float4& a, float4& c) {
    {
        const int u = tx, rr = u >> 4, g = u & 15;
        const int cin = rr / 3, ky = rr - cin * 3, ys = y + ky - 1;
        a = make_float4(0.f, 0.f, 0.f, 0.f);
        if ((unsigned)ys < 64u)
            a = *(const float4*)(x + (((size_t)(b * 16 + cin) * 64 + t) * 4096)
                                   + ys * 64 + g * 4);
    }
    c = make_float4(0.f, 0.f, 0.f, 0.f);
    if (tx < 320) {
        const int u = 448 + tx, rr = u >> 4, g = u & 15;
        const int cin = rr / 3, ky = rr - cin * 3, ys = y + ky - 1;
        if ((unsigned)ys < 64u)
            c = *(const float4*)(x + (((size_t)(b * 16 + cin) * 64 + t) * 4096)
                                   + ys * 64 + g * 4);
    }
}

// ---- pre-kernel: weights -> A-frags (v15/v18-verified grouping) ----
// chunks: 0..11 x (rows rl=cin*3+ky); 12..19 ky1 (own h); 20..27 ky0 (y-1);
// 28..35 ky2 (y+1). Per-row 4 k-slots (q,o), kx=o+2q, phantom at q&o.
__global__ __launch_bounds__(64) void build_wfrag(
    const float* __restrict__ Wx, const float* __restrict__ Wh,
    uint4* __restrict__ wfrag)
{
    const int bid   = blockIdx.x;            // 0..71
    const int mtile = bid / 36, c = bid % 36;
    const int lane  = threadIdx.x;
    const int m     = lane & 31;
    const int grow  = (m < 16) ? (mtile * 16 + m) : (64 + mtile * 16 + (m - 16));
    unsigned short h[8];
    for (int j = 0; j < 8; ++j) {
        const int kl = (lane >> 5) * 8 + j;
        float w = 0.0f;
        if (c < 12) {
            const int k  = c * 16 + kl;
            const int rl = k >> 2, t4 = k & 3;
            const int cin = rl / 3, ky = rl - cin * 3;
            const int o = t4 & 1, q = t4 >> 1, kx = o + 2 * q;
            if (!(q && o)) w = Wx[((size_t)grow * 16 + cin) * 9 + ky * 3 + kx];
        } else {
            const int cg = (c - 12) >> 3;    // 0:ky1 1:ky0 2:ky2
            const int ky = (cg == 0) ? 1 : ((cg == 1) ? 0 : 2);
            const int k  = ((c - 12) & 7) * 16 + kl;
            const int cin = k >> 2, t4 = k & 3;
            const int o = t4 & 1, q = t4 >> 1, kx = o + 2 * q;
            if (!(q && o)) w = Wh[((size_t)grow * 32 + cin) * 9 + ky * 3 + kx];
        }
        _Float16 hw = (_Float16)w;
        h[j] = *(unsigned short*)&hw;
    }
    uint4 o4;
    o4.x = (unsigned)h[0] | ((unsigned)h[1] << 16);
    o4.y = (unsigned)h[2] | ((unsigned)h[3] << 16);
    o4.z = (unsigned)h[4] | ((unsigned)h[5] << 16);
    o4.w = (unsigned)h[6] | ((unsigned)h[7] << 16);
    wfrag[(size_t)bid * 64 + lane] = o4;
}

#define STAGE_ROW(rr, vx, vy, vz, vw)                              \
    do {                                                           \
        float prev_ = __shfl_up((vw), 1);                          \
        if (g == 0) prev_ = 0.f;                                   \
        const int r36_ = (rr) * 36;                                \
        plds[r36_ + 2 * g + 2] = pack2((vx), (vy));                \
        plds[r36_ + 2 * g + 3] = pack2((vz), (vw));                \
        plds[CP1 / 4 + r36_ + 2 * g]     = pack2(prev_, (vx));     \
        plds[CP1 / 4 + r36_ + 2 * g + 1] = pack2((vy), (vz));      \
        if (g == 15) plds[CP1 / 4 + r36_ + 32] = pack2((vw), 0.f); \
    } while (0)

#define MFMA_CHUNK(cc, rbb)                                                  \
    do {                                                                     \
        uint4 aw = wlds[(mtile * 36 + (cc)) * 64 + lane];                    \
        const int B0 = (rbb) * RS;                                           \
        unsigned d0 = *(const unsigned*)(lbase + B0);                        \
        unsigned d1 = *(const unsigned*)(lbase + B0 + 4);                    \
        unsigned e0 = *(const unsigned*)(lbase + B0 + RS);                   \
        unsigned e1 = *(const unsigned*)(lbase + B0 + RS + 4);               \
        uint4 bf; bf.x = d0; bf.y = d1; bf.z = e0; bf.w = e1;                \
        union { uint4 u; half8 h; } ua, ub;                                  \
        ua.u = aw; ub.u = bf;                                                \
        acc = __builtin_amdgcn_mfma_f32_32x32x16_f16(ua.h, ub.h, acc, 0, 0, 0); \
    } while (0)

__global__ __launch_bounds__(512, 1) void convgru_persist(
    const float* __restrict__ x, const float* __restrict__ bx,
    const uint4* __restrict__ wfrag,
    unsigned* __restrict__ hb,   // f16 h slots: 2 x [b][y][1024 dw]
    float* __restrict__ out,     // final NCHW (t=63 only; never aliased)
    int* __restrict__ flags)     // flag[b*64+y] = t  <=> h(t-1) published
{
    __shared__ unsigned plds[LDS_DW];        // staging + scratch (58,880 B)
    __shared__ uint4    wlds[72 * 64];       // A-fragments      (73,728 B)
    __shared__ float    hrow[32 * 64];       // own h(t-1)       ( 8,192 B)

    const int tx = threadIdx.x;
    const int y  = blockIdx.x;               // image row 0..63
    const int b  = blockIdx.y;               // batch 0..3
    const int lane  = tx & 63;
    const int wv    = tx >> 6;               // 0..7
    const int kh    = wv & 1;                // 0: x+ky0, 1: own-h+ky2
    const int tile  = wv >> 1;               // 0..3 (kh pair shares tile)
    const int mtile = tile & 1;
    const int ntile = tile >> 1;
    const int xpx   = ntile * 32 + (lane & 31);
    const int half  = lane >> 5;
    const int lb_off = ((xpx & 1) ? (2 * xpx + 6) : (CP1 + 2 * xpx))
                       + half * (2 * RS);
    const char* lbase = (const char*)plds + lb_off;

    // one-time setup
    #pragma unroll
    for (int i = 0; i < 9; ++i) wlds[i * 512 + tx] = wfrag[i * 512 + tx];
    if (tx < 144) plds[tx * 36 + 34] = 0u;           // copy0 right-halo dword
    ((float4*)hrow)[tx] = make_float4(0.f, 0.f, 0.f, 0.f);   // h0 = 0
    __syncthreads();

    float hcur[8];
    #pragma unroll
    for (int r = 0; r < 8; ++r) hcur[r] = 0.0f;
    float bz[8], bn[8];
    #pragma unroll
    for (int r = 0; r < 8; ++r) {
        const int row = (r & 3) + 8 * (r >> 2) + 4 * half;
        const int oc  = mtile * 16 + row;
        bz[r] = bx[oc]; bn[r] = bx[64 + oc];
    }

    float4 xa = make_float4(0.f, 0.f, 0.f, 0.f), xb = xa;
    if (wv < 7) load_x7(x, b, y, 0, tx, xa, xb);     // prefetch t=0

    #pragma unroll 1
    for (int t = 0; t < 64; ++t) {
        // ---- TOP: wave7 publishes h(t-1) (f16) || waves 0-6 stage local ----
        if (wv == 7) {
            if (t > 0) {
                unsigned* dst = hb + (size_t)((t - 1) & 1) * SLOTDW
                                   + (size_t)(b * 64 + y) * 1024;
                #pragma unroll
                for (int k = 0; k < 4; ++k) {
                    const int dwi = k * 256 + lane * 4;
                    const float* src = hrow + dwi * 2;
                    float4 aa = *(const float4*)(src);
                    float4 bb = *(const float4*)(src + 4);
                    uintx4 pk;
                    pk[0] = pack2(aa.x, aa.y); pk[1] = pack2(aa.z, aa.w);
                    pk[2] = pack2(bb.x, bb.y); pk[3] = pack2(bb.z, bb.w);
                    st_dc4u(dst + dwi, pk);
                }
                drain_vm();                          // row at coherence point
                if (lane == 0)
                    __hip_atomic_store(flags + b * 64 + y, t,
                                       __ATOMIC_RELAXED, __HIP_MEMORY_SCOPE_AGENT);
            }
        } else {
            {   // x rows 0..47, task u = tx
                const int u = tx, rr = u >> 4, g = u & 15;
                STAGE_ROW(rr, xa.x, xa.y, xa.z, xa.w);
            }
            if (tx < 320) {                          // task u = 448+tx
                const int u = 448 + tx, rr = u >> 4, g = u & 15;
                STAGE_ROW(rr, xb.x, xb.y, xb.z, xb.w);
            }
            {   // own-h rows 48..79, task u = tx
                const int cin = tx >> 4, g = tx & 15;
                float4 v = *(const float4*)(hrow + cin * 64 + g * 4);
                STAGE_ROW(48 + cin, v.x, v.y, v.z, v.w);
            }
            if (tx < 64) {                           // task u = 448+tx
                const int u = 448 + tx, cin = u >> 4, g = u & 15;
                float4 v = *(const float4*)(hrow + cin * 64 + g * 4);
                STAGE_ROW(48 + cin, v.x, v.y, v.z, v.w);
            }
        }
        __syncthreads();                             // B1

        // ---- poll + issue halo load (1 dwordx4/thread, f16) ----
        const int s    = tx >> 8;                    // 0: y-1, 1: y+1
        const int hcin = (tx >> 3) & 31;
        const int oct  = tx & 7;                     // col block 8*oct..8*oct+7
        const int yn   = s ? (y + 1) : (y - 1);
        uintx4 hd = (uintx4)(0u);
        const bool doload = (t > 0) && ((unsigned)yn < 64u);
        if (t > 0) {
            if (lane == 0 && y > 0)
                while (__hip_atomic_load(flags + b * 64 + (y - 1), __ATOMIC_RELAXED,
                                         __HIP_MEMORY_SCOPE_AGENT) < t) { }
            if (lane == 1 && y < 63)
                while (__hip_atomic_load(flags + b * 64 + (y + 1), __ATOMIC_RELAXED,
                                         __HIP_MEMORY_SCOPE_AGENT) < t) { }
            __builtin_amdgcn_sched_barrier(0);       // pin loads after spin
        }
        if (doload) {
            const unsigned* p = hb + (size_t)((t - 1) & 1) * SLOTDW
                                   + (size_t)(b * 64 + yn) * 1024
                                   + hcin * 32 + oct * 4;
            ld_issue4(p, hd);
        }

        // ---- local chunks (rows 0..79; overlap the halo load) ----
        floatx16 acc;
        #pragma unroll
        for (int i = 0; i < 16; ++i) acc[i] = 0.0f;
        if (kh == 0) {
            #pragma unroll
            for (int j = 0; j < 12; ++j) MFMA_CHUNK(j, 4 * j);
        } else {
            #pragma unroll
            for (int j = 0; j < 8; ++j) MFMA_CHUNK(12 + j, 48 + 4 * j);
        }

        if (doload) vm_wait4(hd);

        // ---- stage halo rows 80..143 from f16 (copy0 raw, copy1 alignbit) ----
        {
            const int rr  = (s ? 112 : 80) + hcin;
            const int r36 = rr * 36;
            unsigned prev = __shfl_up(hd[3], 1);
            if (oct == 0) prev = 0u;                 // col -1 halo
            plds[r36 + 2 + 4 * oct + 0] = hd[0];
            plds[r36 + 2 + 4 * oct + 1] = hd[1];
            plds[r36 + 2 + 4 * oct + 2] = hd[2];
            plds[r36 + 2 + 4 * oct + 3] = hd[3];
            plds[CP1 / 4 + r36 + 4 * oct]     = (prev >> 16)  | (hd[0] << 16);
            plds[CP1 / 4 + r36 + 4 * oct + 1] = (hd[0] >> 16) | (hd[1] << 16);
            plds[CP1 / 4 + r36 + 4 * oct + 2] = (hd[1] >> 16) | (hd[2] << 16);
            plds[CP1 / 4 + r36 + 4 * oct + 3] = (hd[2] >> 16) | (hd[3] << 16);
            if (oct == 7) plds[CP1 / 4 + r36 + 32] = hd[3] >> 16;  // (63, 64=0)
        }
        __syncthreads();                             // B2

        // ---- remote chunks ----
        if (kh == 0) {
            #pragma unroll
            for (int j = 0; j < 8; ++j) MFMA_CHUNK(20 + j, 80 + 4 * j);
        } else {
            #pragma unroll
            for (int j = 0; j < 8; ++j) MFMA_CHUNK(28 + j, 112 + 4 * j);
            #pragma unroll
            for (int r = 0; r < 16; ++r)
                plds[SCRDW + tile * 1088 + r * 68 + lane] = __float_as_uint(acc[r]);
        }
        __syncthreads();                             // B2'

        // ---- x(t+1) prefetch (drains under epilogue) ----
        if (t < 63 && wv < 7) load_x7(x, b, y, t + 1, tx, xa, xb);

        // ---- kh0: combine + epilogue ----
        if (kh == 0) {
            #pragma unroll
            for (int r = 0; r < 16; ++r)
                acc[r] += __uint_as_float(plds[SCRDW + tile * 1088 + r * 68 + lane]);
            #pragma unroll
            for (int r = 0; r < 8; ++r) {
                const int row = (r & 3) + 8 * (r >> 2) + 4 * half;
                const int oc  = mtile * 16 + row;
                float zp = acc[r]     + bz[r];
                float np = acc[r + 8] + bn[r];
                float z  = 1.0f / (1.0f + __expf(-zp));
                float e  = __expf(2.0f * np);
                float n  = 1.0f - 2.0f / (e + 1.0f);             // tanh
                float hn = (1.0f - z) * hcur[r] + z * n;
                hcur[r] = hn;
                if (t == 63)
                    out[(size_t)(b * 32 + oc) * 4096 + y * 64 + xpx] = hn;
                else
                    hrow[oc * 64 + xpx] = hn;
            }
        }
        __syncthreads();                             // B3: hrow ready
    }
}

extern "C" void kernel_launch(void* const* d_in, const int* in_sizes, int n_in,
                              void* d_out, int out_size, void* d_ws, size_t ws_size,
                              hipStream_t stream) {
    const float* x  = (const float*)d_in[0];
    const float* Wx = (const float*)d_in[1];
    const float* bx = (const float*)d_in[2];
    const float* Wh = (const float*)d_in[3];
    float*    out   = (float*)d_out;                         // write-only
    unsigned* hb    = (unsigned*)d_ws;                       // 2 MB f16 slots
    uint4*    wfrag = (uint4*)((char*)d_ws + (2u << 20));    // 72 KB A-frags
    int*      flags = (int*)((char*)d_ws + (2u << 20) + (80u << 10)); // 1 KB

    (void)hipMemsetAsync(flags, 0, 1024, stream);
    hipLaunchKernelGGL(build_wfrag, dim3(72), dim3(64), 0, stream, Wx, Wh, wfrag);

    void* args[] = { (void*)&x, (void*)&bx, (void*)&wfrag,
                     (void*)&hb, (void*)&out, (void*)&flags };
    (void)hipLaunchCooperativeKernel((const void*)convgru_persist,
                                     dim3(64, 4), dim3(512), args, 0, stream);
}